// Round 4
// baseline (15499.304 us; speedup 1.0000x reference)
//
#include <hip/hip_runtime.h>
#include <stdint.h>

#define S_LEN 512
#define NB    64
#define HID   256
#define G3    768
#define SB    32768   // S_LEN * NB
#define NLAYER 6

typedef short bf16x8 __attribute__((ext_vector_type(8)));
typedef float floatx4 __attribute__((ext_vector_type(4)));
typedef unsigned short u16;
typedef unsigned int   u32;

__device__ __forceinline__ float bf2f(u16 v) {
  u32 u = ((u32)v) << 16;
  return __builtin_bit_cast(float, u);
}
__device__ __forceinline__ u16 f2bf(float f) {
  u32 u = __builtin_bit_cast(u32, f);
  u = (u + 0x7FFFu + ((u >> 16) & 1u)) >> 16;
  return (u16)u;
}
__device__ __forceinline__ float fsigmoid(float x) {
  return __builtin_amdgcn_rcpf(1.0f + __expf(-x));
}
__device__ __forceinline__ float ftanh(float x) {
  return 1.0f - 2.0f * __builtin_amdgcn_rcpf(1.0f + __expf(x + x));
}

// ---------------------------------------------------------------------------
// detect_fp32 / cvt / write_out: dtype-adaptive input handling (round 3).
// ---------------------------------------------------------------------------
__global__ void detect_fp32(const u16* __restrict__ x, int n, int* flag) {
  __shared__ int tot;
  if (threadIdx.x == 0) tot = 0;
  __syncthreads();
  int c = 0;
  for (int i = threadIdx.x; i < n; i += blockDim.x) {
    u16 v = x[i];
    if (((v >> 7) & 0xFF) == 0xFF) ++c;
  }
  atomicAdd(&tot, c);
  __syncthreads();
  if (threadIdx.x == 0) *flag = (tot > 64) ? 1 : 0;
}

__global__ void cvt(const void* __restrict__ src, u16* __restrict__ dst,
                    int n, const int* __restrict__ flag) {
  const int stride = gridDim.x * blockDim.x;
  const bool isf32 = (*flag != 0);
  for (int i = blockIdx.x * blockDim.x + threadIdx.x; i < n; i += stride) {
    if (isf32) dst[i] = f2bf(((const float*)src)[i]);
    else       dst[i] = ((const u16*)src)[i];
  }
}

__global__ void write_out(const float* __restrict__ hNs, void* __restrict__ out,
                          int n, const int* __restrict__ flag) {
  int i = blockIdx.x * blockDim.x + threadIdx.x;
  if (i >= n) return;
  if (*flag) ((float*)out)[i] = hNs[i];
  else       ((u16*)out)[i]   = f2bf(hNs[i]);
}

// ---------------------------------------------------------------------------
// gate_gemm: out[dir][m][n] = sum_k A[m][k] * W[dir][n][k] + bias[dir][n]
// (unchanged from round 3 — verified correct, ~secondary cost)
// ---------------------------------------------------------------------------
__global__ __launch_bounds__(256)
void gate_gemm(const u16* __restrict__ A, const u16* __restrict__ W,
               const u16* __restrict__ bias, u16* __restrict__ outg, int K) {
  const int m0  = blockIdx.x * 128;
  const int n0  = blockIdx.y * 128;
  const int dir = blockIdx.z;
  W    += (size_t)dir * G3 * K;
  bias += (size_t)dir * G3;
  outg += (size_t)dir * (size_t)SB * G3;

  __shared__ __align__(16) u16 lA[8192];
  __shared__ __align__(16) u16 lB[8192];

  const int tid  = threadIdx.x;
  const int lane = tid & 63;
  const int wv   = tid >> 6;
  const int wm   = wv & 1, wn = wv >> 1;
  const int l15  = lane & 15, quad = lane >> 4;

  floatx4 acc[4][4] = {};

  for (int k0 = 0; k0 < K; k0 += 64) {
    bf16x8 ra[4], rb[4];
#pragma unroll
    for (int i = 0; i < 4; ++i) {
      int c   = i * 256 + tid;
      int row = c >> 3;
      int kc  = (c & 7) ^ (row & 7);
      ra[i] = *(const bf16x8*)(A + (size_t)(m0 + row) * K + (k0 + kc * 8));
      rb[i] = *(const bf16x8*)(W + (size_t)(n0 + row) * K + (k0 + kc * 8));
    }
    __syncthreads();
#pragma unroll
    for (int i = 0; i < 4; ++i) {
      *(bf16x8*)(lA + (size_t)(i * 256 + tid) * 8) = ra[i];
      *(bf16x8*)(lB + (size_t)(i * 256 + tid) * 8) = rb[i];
    }
    __syncthreads();

#pragma unroll
    for (int kt = 0; kt < 2; ++kt) {
      bf16x8 af[4], bfr[4];
#pragma unroll
      for (int mt = 0; mt < 4; ++mt) {
        int row = wm * 64 + mt * 16 + l15;
        int ch  = row * 8 + ((kt * 4 + quad) ^ (row & 7));
        af[mt] = *(const bf16x8*)(lA + ch * 8);
      }
#pragma unroll
      for (int nt = 0; nt < 4; ++nt) {
        int row = wn * 64 + nt * 16 + l15;
        int ch  = row * 8 + ((kt * 4 + quad) ^ (row & 7));
        bfr[nt] = *(const bf16x8*)(lB + ch * 8);
      }
#pragma unroll
      for (int mt = 0; mt < 4; ++mt)
#pragma unroll
        for (int nt = 0; nt < 4; ++nt)
          acc[mt][nt] = __builtin_amdgcn_mfma_f32_16x16x32_bf16(
              af[mt], bfr[nt], acc[mt][nt], 0, 0, 0);
    }
  }
  __syncthreads();

#pragma unroll
  for (int nt = 0; nt < 4; ++nt) {
    int n    = n0 + wn * 64 + nt * 16 + l15;
    float bv = bf2f(bias[n]);
#pragma unroll
    for (int mt = 0; mt < 4; ++mt) {
#pragma unroll
      for (int r = 0; r < 4; ++r) {
        int m = m0 + wm * 64 + mt * 16 + quad * 4 + r;
        outg[(size_t)m * G3 + n] = f2bf(acc[mt][nt][r] + bv);
      }
    }
  }
}

// ---------------------------------------------------------------------------
// gru_scan v2: one LDS-only barrier per step; gate math fully in-register.
// 8 WGs (dir x 4 batch-groups of 16), 512 threads = 8 waves.
// Wave wv owns H-columns j in [wv*32, wv*32+32) for ALL 3 gates (6 n-tiles).
// W_hh kt 0..6 stationary in VGPRs (168 regs); kt=7 slice in LDS (48 KB).
// h state: fp32 in registers (lane owns (m=quad*4+r, j) across all steps);
// cross-wave h exchange via double-buffered, XOR-swizzled hbuf.
// ---------------------------------------------------------------------------
__global__ __launch_bounds__(512, 2)
void gru_scan(const u16* __restrict__ gateX,   // [2][SB][768] bf16
              const u16* __restrict__ Whh,     // [2][768][256] (this layer)
              const u16* __restrict__ Bhh,     // [2][768]
              const u16* __restrict__ H0,      // [12][64][256] bf16
              u16* __restrict__ layerOut,      // [SB][512] bf16
              float* __restrict__ hNs,         // fp32 staging [12][64][256]
              int layer) {
  const int dir  = blockIdx.x & 1;
  const int bg   = blockIdx.x >> 1;
  const int tid  = threadIdx.x;
  const int lane = tid & 63;
  const int wv   = tid >> 6;
  const int l15  = lane & 15, quad = lane >> 4;

  __shared__ __align__(16) u16 hbuf[2][16 * 256];   // 2 x 8 KB, swizzled 16B chunks
  __shared__ __align__(16) u16 whT[768 * 32];       // Whh k in [224,256), 48 KB

  const u16* Wd = Whh + (size_t)dir * G3 * HID;

  // ---- stage whT (kt=7 k-slice), XOR-swizzled 16B chunks ----
  for (int it = 0; it < 6; ++it) {
    int cl  = tid + it * 512;          // 0..3071
    int row = cl >> 2, c = cl & 3;
    bf16x8 v = *(const bf16x8*)(Wd + row * HID + 224 + c * 8);
    *(bf16x8*)((char*)whT + row * 64 + ((c ^ (row & 3)) * 16)) = v;
  }

  // ---- stationary W_hh fragments, kt 0..6 (B-layout: n=l15-row, k=quad*8+e) --
  bf16x8 wfr[7][6];
#pragma unroll
  for (int nt = 0; nt < 6; ++nt) {
    int n = (nt >> 1) * 256 + wv * 32 + (nt & 1) * 16 + l15;
#pragma unroll
    for (int kt = 0; kt < 7; ++kt)
      wfr[kt][nt] = *(const bf16x8*)(Wd + (size_t)n * HID + kt * 32 + quad * 8);
  }
  float bh[6];
#pragma unroll
  for (int nt = 0; nt < 6; ++nt)
    bh[nt] = bf2f(Bhh[dir * G3 + (nt >> 1) * 256 + wv * 32 + (nt & 1) * 16 + l15]);

  // ---- h_prev in registers; seed hbuf[1] (read by t=0 MFMA) ----
  float hprev[2][4];
#pragma unroll
  for (int jt = 0; jt < 2; ++jt)
#pragma unroll
    for (int r = 0; r < 4; ++r) {
      int j = wv * 32 + jt * 16 + l15;
      int m = quad * 4 + r;
      u16 hv = H0[((size_t)(layer * 2 + dir) * NB + bg * 16 + m) * HID + j];
      hprev[jt][r] = bf2f(hv);
      int ch = j >> 3;
      int sw = (ch & 24) | ((ch & 7) ^ (m & 7));
      *(u16*)((char*)hbuf[1] + m * 512 + sw * 16 + (j & 7) * 2) = hv;
    }
  __syncthreads();

  const size_t dbase = (size_t)dir * SB * G3;

  for (int t = 0; t < S_LEN; ++t) {
    const int s = dir ? (S_LEN - 1 - t) : t;

    // ---- x-gate loads for this step (latency covered by MFMA phase) ----
    const u16* xb = gateX + dbase + ((size_t)s * NB + bg * 16) * G3;
    u16 xv[3][2][4];
#pragma unroll
    for (int g = 0; g < 3; ++g)
#pragma unroll
      for (int jt = 0; jt < 2; ++jt)
#pragma unroll
        for (int r = 0; r < 4; ++r)
          xv[g][jt][r] =
              xb[(quad * 4 + r) * G3 + g * 256 + wv * 32 + jt * 16 + l15];

    // ---- MFMA phase: preacts = h @ Whh^T + b_hh for this wave's 6 n-tiles --
    const char* hrd = (const char*)hbuf[(t & 1) ^ 1];
    floatx4 acc[6];
#pragma unroll
    for (int nt = 0; nt < 6; ++nt) {
      floatx4 v = {bh[nt], bh[nt], bh[nt], bh[nt]};
      acc[nt] = v;
    }
#pragma unroll
    for (int kt = 0; kt < 8; ++kt) {
      bf16x8 af = *(const bf16x8*)(hrd + l15 * 512 + (kt >> 1) * 128 +
                                   (((kt & 1) * 4 + quad) ^ (l15 & 7)) * 16);
      if (kt < 7) {
#pragma unroll
        for (int nt = 0; nt < 6; ++nt)
          acc[nt] = __builtin_amdgcn_mfma_f32_16x16x32_bf16(af, wfr[kt][nt],
                                                            acc[nt], 0, 0, 0);
      } else {
#pragma unroll
        for (int nt = 0; nt < 6; ++nt) {
          int n = (nt >> 1) * 256 + wv * 32 + (nt & 1) * 16 + l15;
          bf16x8 bw = *(const bf16x8*)((const char*)whT + n * 64 +
                                       ((quad ^ (l15 & 3)) * 16));
          acc[nt] = __builtin_amdgcn_mfma_f32_16x16x32_bf16(af, bw,
                                                            acc[nt], 0, 0, 0);
        }
      }
    }

    // ---- gate phase: fully in-register (lane owns (m=quad*4+r, j)) ----
    char* hwr = (char*)hbuf[t & 1];
    u16* lout = layerOut + (size_t)s * NB * 512;
#pragma unroll
    for (int jt = 0; jt < 2; ++jt)
#pragma unroll
      for (int r = 0; r < 4; ++r) {
        float xr = bf2f(xv[0][jt][r]);
        float xz = bf2f(xv[1][jt][r]);
        float xn = bf2f(xv[2][jt][r]);
        float rg = fsigmoid(xr + acc[0 + jt][r]);
        float zg = fsigmoid(xz + acc[2 + jt][r]);
        float ng = ftanh(xn + rg * acc[4 + jt][r]);
        float h  = (1.0f - zg) * ng + zg * hprev[jt][r];
        hprev[jt][r] = h;
        u16 hb = f2bf(h);
        int j  = wv * 32 + jt * 16 + l15;
        int m  = quad * 4 + r;
        int ch = j >> 3;
        int sw = (ch & 24) | ((ch & 7) ^ (m & 7));
        *(u16*)(hwr + m * 512 + sw * 16 + (j & 7) * 2) = hb;
        lout[(size_t)(bg * 16 + m) * 512 + dir * 256 + j] = hb;
        if (t == S_LEN - 1)
          hNs[((size_t)(layer * 2 + dir) * NB + bg * 16 + m) * HID + j] = h;
      }

    // LDS-drain-only barrier: global loads/stores stay in flight across it.
    asm volatile("s_waitcnt lgkmcnt(0)\n\ts_barrier" ::: "memory");
  }
}

// ---------------------------------------------------------------------------
extern "C" void kernel_launch(void* const* d_in, const int* in_sizes, int n_in,
                              void* d_out, int out_size, void* d_ws, size_t ws_size,
                              hipStream_t stream) {
  (void)n_in; (void)ws_size;
  char* ws = (char*)d_ws;
  int*   flag  = (int*)ws;
  float* hNs   = (float*)(ws + 4096);
  u16*   h0C   = (u16*)(ws + (1u << 20));
  u16*   wih0C = h0C   + 196608;
  u16*   wihC  = wih0C + 196608;
  u16*   whhC  = wihC  + 3932160;
  u16*   bihC  = whhC  + 2359296;
  u16*   bhhC  = bihC  + 9216;
  u16*   gateX = (u16*)(ws + (16u  << 20));
  u16*   bufA  = (u16*)(ws + (112u << 20));
  u16*   bufB  = (u16*)(ws + (144u << 20));
  u16*   xC    = bufB;   // aliased; layer-0 gemm consumes it before bufB written

  detect_fp32<<<1, 1024, 0, stream>>>((const u16*)d_in[0], 262144, flag);
  cvt<<<512, 256, 0, stream>>>(d_in[0], xC,    in_sizes[0], flag);
  cvt<<<256, 256, 0, stream>>>(d_in[1], h0C,   in_sizes[1], flag);
  cvt<<<256, 256, 0, stream>>>(d_in[2], wih0C, in_sizes[2], flag);
  cvt<<<512, 256, 0, stream>>>(d_in[3], wihC,  in_sizes[3], flag);
  cvt<<<512, 256, 0, stream>>>(d_in[4], whhC,  in_sizes[4], flag);
  cvt<<< 64, 256, 0, stream>>>(d_in[5], bihC,  in_sizes[5], flag);
  cvt<<< 64, 256, 0, stream>>>(d_in[6], bhhC,  in_sizes[6], flag);

  for (int layer = 0; layer < NLAYER; ++layer) {
    const u16* inp = (layer == 0) ? xC : ((layer & 1) ? bufA : bufB);
    u16* outBuf    = (layer & 1) ? bufB : bufA;

    const int K = (layer == 0) ? 128 : 512;
    const u16* W = (layer == 0) ? wih0C
                                : (wihC + (size_t)(layer - 1) * 2 * G3 * 512);
    dim3 grid(256, 6, 2);
    gate_gemm<<<grid, 256, 0, stream>>>(inp, W, bihC + (size_t)layer * 2 * G3,
                                        gateX, K);
    gru_scan<<<8, 512, 0, stream>>>(gateX, whhC + (size_t)layer * 2 * G3 * HID,
                                    bhhC + (size_t)layer * 2 * G3, h0C,
                                    outBuf, hNs, layer);
  }
  write_out<<<(out_size + 255) / 256, 256, 0, stream>>>(hNs, d_out, out_size, flag);
}

// Round 5
// 14498.586 us; speedup vs baseline: 1.0690x; 1.0690x over previous
//
#include <hip/hip_runtime.h>
#include <stdint.h>

#define S_LEN 512
#define NB    64
#define HID   256
#define G3    768
#define SB    32768   // S_LEN * NB
#define NLAYER 6

typedef short bf16x8 __attribute__((ext_vector_type(8)));
typedef float floatx4 __attribute__((ext_vector_type(4)));
typedef unsigned short u16;
typedef unsigned int   u32;

__device__ __forceinline__ float bf2f(u16 v) {
  u32 u = ((u32)v) << 16;
  return __builtin_bit_cast(float, u);
}
__device__ __forceinline__ u16 f2bf(float f) {
  u32 u = __builtin_bit_cast(u32, f);
  u = (u + 0x7FFFu + ((u >> 16) & 1u)) >> 16;
  return (u16)u;
}
__device__ __forceinline__ float fsigmoid(float x) {
  return __builtin_amdgcn_rcpf(1.0f + __expf(-x));
}
__device__ __forceinline__ float ftanh(float x) {
  return 1.0f - 2.0f * __builtin_amdgcn_rcpf(1.0f + __expf(x + x));
}

// ---------------------------------------------------------------------------
// detect_fp32 / cvt / write_out: dtype-adaptive input handling.
// ---------------------------------------------------------------------------
__global__ void detect_fp32(const u16* __restrict__ x, int n, int* flag) {
  __shared__ int tot;
  if (threadIdx.x == 0) tot = 0;
  __syncthreads();
  int c = 0;
  for (int i = threadIdx.x; i < n; i += blockDim.x) {
    u16 v = x[i];
    if (((v >> 7) & 0xFF) == 0xFF) ++c;
  }
  atomicAdd(&tot, c);
  __syncthreads();
  if (threadIdx.x == 0) *flag = (tot > 64) ? 1 : 0;
}

__global__ void cvt(const void* __restrict__ src, u16* __restrict__ dst,
                    int n, const int* __restrict__ flag) {
  const int stride = gridDim.x * blockDim.x;
  const bool isf32 = (*flag != 0);
  for (int i = blockIdx.x * blockDim.x + threadIdx.x; i < n; i += stride) {
    if (isf32) dst[i] = f2bf(((const float*)src)[i]);
    else       dst[i] = ((const u16*)src)[i];
  }
}

__global__ void write_out(const float* __restrict__ hNs, void* __restrict__ out,
                          int n, const int* __restrict__ flag) {
  int i = blockIdx.x * blockDim.x + threadIdx.x;
  if (i >= n) return;
  if (*flag) ((float*)out)[i] = hNs[i];
  else       ((u16*)out)[i]   = f2bf(hNs[i]);
}

// ---------------------------------------------------------------------------
// gate_gemm: out[dir][m][n] = A[m][:] . W[dir][n][:] + b_ih[n] (+ b_hh[n] for
// the r/z gates, n<512 -- folded here so the scan only handles the n-gate's
// b_hh, which the reference keeps inside r*(.)).
// ---------------------------------------------------------------------------
__global__ __launch_bounds__(256)
void gate_gemm(const u16* __restrict__ A, const u16* __restrict__ W,
               const u16* __restrict__ bias_ih, const u16* __restrict__ bias_hh,
               u16* __restrict__ outg, int K) {
  const int m0  = blockIdx.x * 128;
  const int n0  = blockIdx.y * 128;
  const int dir = blockIdx.z;
  W       += (size_t)dir * G3 * K;
  bias_ih += (size_t)dir * G3;
  bias_hh += (size_t)dir * G3;
  outg    += (size_t)dir * (size_t)SB * G3;

  __shared__ __align__(16) u16 lA[8192];
  __shared__ __align__(16) u16 lB[8192];

  const int tid  = threadIdx.x;
  const int lane = tid & 63;
  const int wv   = tid >> 6;
  const int wm   = wv & 1, wn = wv >> 1;
  const int l15  = lane & 15, quad = lane >> 4;

  floatx4 acc[4][4] = {};

  for (int k0 = 0; k0 < K; k0 += 64) {
    bf16x8 ra[4], rb[4];
#pragma unroll
    for (int i = 0; i < 4; ++i) {
      int c   = i * 256 + tid;
      int row = c >> 3;
      int kc  = (c & 7) ^ (row & 7);
      ra[i] = *(const bf16x8*)(A + (size_t)(m0 + row) * K + (k0 + kc * 8));
      rb[i] = *(const bf16x8*)(W + (size_t)(n0 + row) * K + (k0 + kc * 8));
    }
    __syncthreads();
#pragma unroll
    for (int i = 0; i < 4; ++i) {
      *(bf16x8*)(lA + (size_t)(i * 256 + tid) * 8) = ra[i];
      *(bf16x8*)(lB + (size_t)(i * 256 + tid) * 8) = rb[i];
    }
    __syncthreads();

#pragma unroll
    for (int kt = 0; kt < 2; ++kt) {
      bf16x8 af[4], bfr[4];
#pragma unroll
      for (int mt = 0; mt < 4; ++mt) {
        int row = wm * 64 + mt * 16 + l15;
        int ch  = row * 8 + ((kt * 4 + quad) ^ (row & 7));
        af[mt] = *(const bf16x8*)(lA + ch * 8);
      }
#pragma unroll
      for (int nt = 0; nt < 4; ++nt) {
        int row = wn * 64 + nt * 16 + l15;
        int ch  = row * 8 + ((kt * 4 + quad) ^ (row & 7));
        bfr[nt] = *(const bf16x8*)(lB + ch * 8);
      }
#pragma unroll
      for (int mt = 0; mt < 4; ++mt)
#pragma unroll
        for (int nt = 0; nt < 4; ++nt)
          acc[mt][nt] = __builtin_amdgcn_mfma_f32_16x16x32_bf16(
              af[mt], bfr[nt], acc[mt][nt], 0, 0, 0);
    }
  }
  __syncthreads();

#pragma unroll
  for (int nt = 0; nt < 4; ++nt) {
    int n    = n0 + wn * 64 + nt * 16 + l15;
    float bv = bf2f(bias_ih[n]) + ((n < 512) ? bf2f(bias_hh[n]) : 0.0f);
#pragma unroll
    for (int mt = 0; mt < 4; ++mt) {
#pragma unroll
      for (int r = 0; r < 4; ++r) {
        int m = m0 + wm * 64 + mt * 16 + quad * 4 + r;
        outg[(size_t)m * G3 + n] = f2bf(acc[mt][nt][r] + bv);
      }
    }
  }
}

// ---------------------------------------------------------------------------
// gru_scan v3 = v2 + weights ACTUALLY stationary.
// The empty asm pin makes each fragment's def opaque -> the compiler can no
// longer rematerialize the (provably invariant) global loads inside the
// t-loop, which is what silently turned rounds 3/4 into L2-BW-bound reload
// loops (VGPR_Count=128 was the tell). Budget: wfr 168 + acc 24 + hprev 8 +
// xv 24 + misc ~ 245 < 256-reg cap at 2 waves/SIMD (launch_bounds(512,2)).
// ---------------------------------------------------------------------------
__global__ __launch_bounds__(512, 2)
void gru_scan(const u16* __restrict__ gateX,   // [2][SB][768] bf16
              const u16* __restrict__ Whh,     // [2][768][256] (this layer)
              const u16* __restrict__ Bhh,     // [2][768]
              const u16* __restrict__ H0,      // [12][64][256] bf16
              u16* __restrict__ layerOut,      // [SB][512] bf16
              float* __restrict__ hNs,         // fp32 staging [12][64][256]
              int layer) {
  const int dir  = blockIdx.x & 1;
  const int bg   = blockIdx.x >> 1;
  const int tid  = threadIdx.x;
  const int lane = tid & 63;
  const int wv   = tid >> 6;
  const int l15  = lane & 15, quad = lane >> 4;

  __shared__ __align__(16) u16 hbuf[2][16 * 256];   // 2 x 8 KB, swizzled 16B chunks
  __shared__ __align__(16) u16 whT[768 * 32];       // Whh k in [224,256), 48 KB

  const u16* Wd = Whh + (size_t)dir * G3 * HID;

  // ---- stage whT (kt=7 k-slice), XOR-swizzled 16B chunks ----
  for (int it = 0; it < 6; ++it) {
    int cl  = tid + it * 512;          // 0..3071
    int row = cl >> 2, c = cl & 3;
    bf16x8 v = *(const bf16x8*)(Wd + row * HID + 224 + c * 8);
    *(bf16x8*)((char*)whT + row * 64 + ((c ^ (row & 3)) * 16)) = v;
  }

  // ---- stationary W_hh fragments, kt 0..6 (B-layout: n=l15-row, k=quad*8+e) --
  bf16x8 wfr[7][6];
#pragma unroll
  for (int nt = 0; nt < 6; ++nt) {
    int n = (nt >> 1) * 256 + wv * 32 + (nt & 1) * 16 + l15;
#pragma unroll
    for (int kt = 0; kt < 7; ++kt)
      wfr[kt][nt] = *(const bf16x8*)(Wd + (size_t)n * HID + kt * 32 + quad * 8);
  }
  // PIN: opaque defs -> no remat, must stay resident in registers.
#pragma unroll
  for (int kt = 0; kt < 7; ++kt)
#pragma unroll
    for (int nt = 0; nt < 6; ++nt)
      asm volatile("" : "+v"(wfr[kt][nt]));

  // n-gate b_hh only (r/z b_hh folded into gateX by gate_gemm)
  float bh2[2];
#pragma unroll
  for (int jt = 0; jt < 2; ++jt)
    bh2[jt] = bf2f(Bhh[dir * G3 + 512 + wv * 32 + jt * 16 + l15]);

  // ---- h_prev in registers; seed hbuf[1] (read by t=0 MFMA) ----
  float hprev[2][4];
#pragma unroll
  for (int jt = 0; jt < 2; ++jt)
#pragma unroll
    for (int r = 0; r < 4; ++r) {
      int j = wv * 32 + jt * 16 + l15;
      int m = quad * 4 + r;
      u16 hv = H0[((size_t)(layer * 2 + dir) * NB + bg * 16 + m) * HID + j];
      hprev[jt][r] = bf2f(hv);
      int ch = j >> 3;
      int sw = (ch & 24) | ((ch & 7) ^ (m & 7));
      *(u16*)((char*)hbuf[1] + m * 512 + sw * 16 + (j & 7) * 2) = hv;
    }
  __syncthreads();

  const size_t dbase = (size_t)dir * SB * G3;

  for (int t = 0; t < S_LEN; ++t) {
    const int s = dir ? (S_LEN - 1 - t) : t;

    // ---- x-gate loads (latency covered by MFMA phase) ----
    const u16* xb = gateX + dbase + ((size_t)s * NB + bg * 16) * G3;
    u16 xv[3][2][4];
#pragma unroll
    for (int g = 0; g < 3; ++g)
#pragma unroll
      for (int jt = 0; jt < 2; ++jt)
#pragma unroll
        for (int r = 0; r < 4; ++r)
          xv[g][jt][r] =
              xb[(quad * 4 + r) * G3 + g * 256 + wv * 32 + jt * 16 + l15];

    // ---- MFMA phase: preacts for this wave's 6 n-tiles ----
    const char* hrd = (const char*)hbuf[(t & 1) ^ 1];
    floatx4 acc[6];
#pragma unroll
    for (int nt = 0; nt < 6; ++nt) {
      if (nt < 4) {
        floatx4 z = {0.0f, 0.0f, 0.0f, 0.0f};
        acc[nt] = z;
      } else {
        floatx4 v = {bh2[nt - 4], bh2[nt - 4], bh2[nt - 4], bh2[nt - 4]};
        acc[nt] = v;
      }
    }
#pragma unroll
    for (int kt = 0; kt < 8; ++kt) {
      bf16x8 af = *(const bf16x8*)(hrd + l15 * 512 + (kt >> 1) * 128 +
                                   (((kt & 1) * 4 + quad) ^ (l15 & 7)) * 16);
      if (kt < 7) {
#pragma unroll
        for (int nt = 0; nt < 6; ++nt)
          acc[nt] = __builtin_amdgcn_mfma_f32_16x16x32_bf16(af, wfr[kt][nt],
                                                            acc[nt], 0, 0, 0);
      } else {
#pragma unroll
        for (int nt = 0; nt < 6; ++nt) {
          int n = (nt >> 1) * 256 + wv * 32 + (nt & 1) * 16 + l15;
          bf16x8 bw = *(const bf16x8*)((const char*)whT + n * 64 +
                                       ((quad ^ (l15 & 3)) * 16));
          acc[nt] = __builtin_amdgcn_mfma_f32_16x16x32_bf16(af, bw,
                                                            acc[nt], 0, 0, 0);
        }
      }
    }

    // ---- gate phase: fully in-register (lane owns (m=quad*4+r, j)) ----
    char* hwr = (char*)hbuf[t & 1];
    u16* lout = layerOut + (size_t)s * NB * 512;
#pragma unroll
    for (int jt = 0; jt < 2; ++jt)
#pragma unroll
      for (int r = 0; r < 4; ++r) {
        float xr = bf2f(xv[0][jt][r]);
        float xz = bf2f(xv[1][jt][r]);
        float xn = bf2f(xv[2][jt][r]);
        float rg = fsigmoid(xr + acc[0 + jt][r]);
        float zg = fsigmoid(xz + acc[2 + jt][r]);
        float ng = ftanh(xn + rg * acc[4 + jt][r]);
        float h  = (1.0f - zg) * ng + zg * hprev[jt][r];
        hprev[jt][r] = h;
        u16 hb = f2bf(h);
        int j  = wv * 32 + jt * 16 + l15;
        int m  = quad * 4 + r;
        int ch = j >> 3;
        int sw = (ch & 24) | ((ch & 7) ^ (m & 7));
        *(u16*)(hwr + m * 512 + sw * 16 + (j & 7) * 2) = hb;
        lout[(size_t)(bg * 16 + m) * 512 + dir * 256 + j] = hb;
        if (t == S_LEN - 1)
          hNs[((size_t)(layer * 2 + dir) * NB + bg * 16 + m) * HID + j] = h;
      }

    // LDS-drain-only barrier: global loads/stores stay in flight across it.
    asm volatile("s_waitcnt lgkmcnt(0)\n\ts_barrier" ::: "memory");
  }
}

// ---------------------------------------------------------------------------
extern "C" void kernel_launch(void* const* d_in, const int* in_sizes, int n_in,
                              void* d_out, int out_size, void* d_ws, size_t ws_size,
                              hipStream_t stream) {
  (void)n_in; (void)ws_size;
  char* ws = (char*)d_ws;
  int*   flag  = (int*)ws;
  float* hNs   = (float*)(ws + 4096);
  u16*   h0C   = (u16*)(ws + (1u << 20));
  u16*   wih0C = h0C   + 196608;
  u16*   wihC  = wih0C + 196608;
  u16*   whhC  = wihC  + 3932160;
  u16*   bihC  = whhC  + 2359296;
  u16*   bhhC  = bihC  + 9216;
  u16*   gateX = (u16*)(ws + (16u  << 20));
  u16*   bufA  = (u16*)(ws + (112u << 20));
  u16*   bufB  = (u16*)(ws + (144u << 20));
  u16*   xC    = bufB;   // aliased; layer-0 gemm consumes it before bufB written

  detect_fp32<<<1, 1024, 0, stream>>>((const u16*)d_in[0], 262144, flag);
  cvt<<<512, 256, 0, stream>>>(d_in[0], xC,    in_sizes[0], flag);
  cvt<<<256, 256, 0, stream>>>(d_in[1], h0C,   in_sizes[1], flag);
  cvt<<<256, 256, 0, stream>>>(d_in[2], wih0C, in_sizes[2], flag);
  cvt<<<512, 256, 0, stream>>>(d_in[3], wihC,  in_sizes[3], flag);
  cvt<<<512, 256, 0, stream>>>(d_in[4], whhC,  in_sizes[4], flag);
  cvt<<< 64, 256, 0, stream>>>(d_in[5], bihC,  in_sizes[5], flag);
  cvt<<< 64, 256, 0, stream>>>(d_in[6], bhhC,  in_sizes[6], flag);

  for (int layer = 0; layer < NLAYER; ++layer) {
    const u16* inp = (layer == 0) ? xC : ((layer & 1) ? bufA : bufB);
    u16* outBuf    = (layer & 1) ? bufB : bufA;

    const int K = (layer == 0) ? 128 : 512;
    const u16* W = (layer == 0) ? wih0C
                                : (wihC + (size_t)(layer - 1) * 2 * G3 * 512);
    dim3 grid(256, 6, 2);
    gate_gemm<<<grid, 256, 0, stream>>>(inp, W, bihC + (size_t)layer * 2 * G3,
                                        bhhC + (size_t)layer * 2 * G3, gateX, K);
    gru_scan<<<8, 512, 0, stream>>>(gateX, whhC + (size_t)layer * 2 * G3 * HID,
                                    bhhC + (size_t)layer * 2 * G3, h0C,
                                    outBuf, hNs, layer);
  }
  write_out<<<(out_size + 255) / 256, 256, 0, stream>>>(hNs, d_out, out_size, flag);
}

// Round 6
// 10664.336 us; speedup vs baseline: 1.4534x; 1.3595x over previous
//
#include <hip/hip_runtime.h>
#include <stdint.h>

#define S_LEN 512
#define NB    64
#define HID   256
#define G3    768
#define SB    32768   // S_LEN * NB
#define NLAYER 6

typedef short bf16x8 __attribute__((ext_vector_type(8)));
typedef float floatx4 __attribute__((ext_vector_type(4)));
typedef unsigned short u16;
typedef unsigned int   u32;

__device__ __forceinline__ float bf2f(u16 v) {
  u32 u = ((u32)v) << 16;
  return __builtin_bit_cast(float, u);
}
__device__ __forceinline__ u16 f2bf(float f) {
  u32 u = __builtin_bit_cast(u32, f);
  u = (u + 0x7FFFu + ((u >> 16) & 1u)) >> 16;
  return (u16)u;
}
__device__ __forceinline__ float fsigmoid(float x) {
  return __builtin_amdgcn_rcpf(1.0f + __expf(-x));
}
__device__ __forceinline__ float ftanh(float x) {
  return 1.0f - 2.0f * __builtin_amdgcn_rcpf(1.0f + __expf(x + x));
}

// ---------------------------------------------------------------------------
// detect_fp32 / cvt / write_out: dtype-adaptive input handling.
// ---------------------------------------------------------------------------
__global__ void detect_fp32(const u16* __restrict__ x, int n, int* flag) {
  __shared__ int tot;
  if (threadIdx.x == 0) tot = 0;
  __syncthreads();
  int c = 0;
  for (int i = threadIdx.x; i < n; i += blockDim.x) {
    u16 v = x[i];
    if (((v >> 7) & 0xFF) == 0xFF) ++c;
  }
  atomicAdd(&tot, c);
  __syncthreads();
  if (threadIdx.x == 0) *flag = (tot > 64) ? 1 : 0;
}

__global__ void cvt(const void* __restrict__ src, u16* __restrict__ dst,
                    int n, const int* __restrict__ flag) {
  const int stride = gridDim.x * blockDim.x;
  const bool isf32 = (*flag != 0);
  for (int i = blockIdx.x * blockDim.x + threadIdx.x; i < n; i += stride) {
    if (isf32) dst[i] = f2bf(((const float*)src)[i]);
    else       dst[i] = ((const u16*)src)[i];
  }
}

__global__ void write_out(const float* __restrict__ hNs, void* __restrict__ out,
                          int n, const int* __restrict__ flag) {
  int i = blockIdx.x * blockDim.x + threadIdx.x;
  if (i >= n) return;
  if (*flag) ((float*)out)[i] = hNs[i];
  else       ((u16*)out)[i]   = f2bf(hNs[i]);
}

// ---------------------------------------------------------------------------
// gate_gemm: preacts = A . W^T + b_ih (+ b_hh for r/z gates), written in the
// PERMUTED gateXp layout so the scan loads its 24 values as 3 coalesced
// bf16x8 vectors:
//   P(dir,s,bg,g,wv,lane,e) ; bg=batch-group(16 rows), lane=quad*16+l15,
//   e = jt*4+r encodes (n-16-block jt, C-reg r). Value = preact at
//   batch b=bg*16+quad*4+r, col n=g*256+wv*32+jt*16+l15.
// ---------------------------------------------------------------------------
__global__ __launch_bounds__(256)
void gate_gemm(const u16* __restrict__ A, const u16* __restrict__ W,
               const u16* __restrict__ bias_ih, const u16* __restrict__ bias_hh,
               u16* __restrict__ outg, int K) {
  const int m0  = blockIdx.x * 128;
  const int n0  = blockIdx.y * 128;
  const int dir = blockIdx.z;
  W       += (size_t)dir * G3 * K;
  bias_ih += (size_t)dir * G3;
  bias_hh += (size_t)dir * G3;

  __shared__ __align__(16) u16 lA[8192];
  __shared__ __align__(16) u16 lB[8192];

  const int tid  = threadIdx.x;
  const int lane = tid & 63;
  const int wv   = tid >> 6;
  const int wm   = wv & 1, wn = wv >> 1;
  const int l15  = lane & 15, quad = lane >> 4;

  floatx4 acc[4][4] = {};

  for (int k0 = 0; k0 < K; k0 += 64) {
    bf16x8 ra[4], rb[4];
#pragma unroll
    for (int i = 0; i < 4; ++i) {
      int c   = i * 256 + tid;
      int row = c >> 3;
      int kc  = (c & 7) ^ (row & 7);
      ra[i] = *(const bf16x8*)(A + (size_t)(m0 + row) * K + (k0 + kc * 8));
      rb[i] = *(const bf16x8*)(W + (size_t)(n0 + row) * K + (k0 + kc * 8));
    }
    __syncthreads();
#pragma unroll
    for (int i = 0; i < 4; ++i) {
      *(bf16x8*)(lA + (size_t)(i * 256 + tid) * 8) = ra[i];
      *(bf16x8*)(lB + (size_t)(i * 256 + tid) * 8) = rb[i];
    }
    __syncthreads();

#pragma unroll
    for (int kt = 0; kt < 2; ++kt) {
      bf16x8 af[4], bfr[4];
#pragma unroll
      for (int mt = 0; mt < 4; ++mt) {
        int row = wm * 64 + mt * 16 + l15;
        int ch  = row * 8 + ((kt * 4 + quad) ^ (row & 7));
        af[mt] = *(const bf16x8*)(lA + ch * 8);
      }
#pragma unroll
      for (int nt = 0; nt < 4; ++nt) {
        int row = wn * 64 + nt * 16 + l15;
        int ch  = row * 8 + ((kt * 4 + quad) ^ (row & 7));
        bfr[nt] = *(const bf16x8*)(lB + ch * 8);
      }
#pragma unroll
      for (int mt = 0; mt < 4; ++mt)
#pragma unroll
        for (int nt = 0; nt < 4; ++nt)
          acc[mt][nt] = __builtin_amdgcn_mfma_f32_16x16x32_bf16(
              af[mt], bfr[nt], acc[mt][nt], 0, 0, 0);
    }
  }
  __syncthreads();

  // epilogue: permuted-layout scatter. Wave's 64 m-rows = one s-block.
  const int sblk = (m0 >> 6) + wm;   // m0=bx*128 -> s = bx*2 + wm
#pragma unroll
  for (int nt = 0; nt < 4; ++nt) {
    int n   = n0 + wn * 64 + nt * 16 + l15;
    int g   = n >> 8;
    int j   = n & 255;
    int wvs = j >> 5;
    int jt  = (j >> 4) & 1;
    float bv = bf2f(bias_ih[n]) + ((n < 512) ? bf2f(bias_hh[n]) : 0.0f);
#pragma unroll
    for (int mt = 0; mt < 4; ++mt) {
#pragma unroll
      for (int r = 0; r < 4; ++r) {
        size_t P = ((((((size_t)dir * 512 + sblk) * 4 + mt) * 3 + g) * 8 + wvs)
                        * 64 + quad * 16 + l15) * 8 + jt * 4 + r;
        outg[P] = f2bf(acc[mt][nt][r] + bv);
      }
    }
  }
}

// ---------------------------------------------------------------------------
// gru_scan v4: single LDS-only barrier + fully-VECTOR VMEM.
//  - x-gates: 3 coalesced bf16x8 loads from permuted gateXp.
//  - layerOut: staged via hbuf -> 1 ds_read_b128 + 1 coalesced 16B store
//    per thread per step (at the top of the NEXT step; epilogue after loop).
//  - weights: wfr kt 0..6 pinned in regs/AGPRs, kt=7 slice in LDS (whT).
// ---------------------------------------------------------------------------
__global__ __attribute__((amdgpu_waves_per_eu(2, 2))) __launch_bounds__(512)
void gru_scan(const u16* __restrict__ gateXp,  // permuted, 2*SB*G3
              const u16* __restrict__ Whh,     // [2][768][256] (this layer)
              const u16* __restrict__ Bhh,     // [2][768]
              const u16* __restrict__ H0,      // [12][64][256] bf16
              u16* __restrict__ layerOut,      // [SB][512] bf16 row-major
              float* __restrict__ hNs,         // fp32 staging [12][64][256]
              int layer) {
  const int dir  = blockIdx.x & 1;
  const int bg   = blockIdx.x >> 1;
  const int tid  = threadIdx.x;
  const int lane = tid & 63;
  const int wv   = tid >> 6;
  const int l15  = lane & 15, quad = lane >> 4;

  __shared__ __align__(16) u16 hbuf[2][16 * 256];   // 2 x 8 KB, swizzled 16B chunks
  __shared__ __align__(16) u16 whT[768 * 32];       // Whh k in [224,256), 48 KB

  const u16* Wd = Whh + (size_t)dir * G3 * HID;

  // ---- stage whT (kt=7 k-slice), XOR-swizzled 16B chunks ----
  for (int it = 0; it < 6; ++it) {
    int cl  = tid + it * 512;          // 0..3071
    int row = cl >> 2, c = cl & 3;
    bf16x8 v = *(const bf16x8*)(Wd + row * HID + 224 + c * 8);
    *(bf16x8*)((char*)whT + row * 64 + ((c ^ (row & 3)) * 16)) = v;
  }

  // ---- stationary W_hh fragments, kt 0..6 (B-layout: n=l15-row, k=quad*8+e) --
  bf16x8 wfr[7][6];
#pragma unroll
  for (int nt = 0; nt < 6; ++nt) {
    int n = (nt >> 1) * 256 + wv * 32 + (nt & 1) * 16 + l15;
#pragma unroll
    for (int kt = 0; kt < 7; ++kt)
      wfr[kt][nt] = *(const bf16x8*)(Wd + (size_t)n * HID + kt * 32 + quad * 8);
  }
  // PIN: opaque defs -> no remat; resident in VGPR/AGPR.
#pragma unroll
  for (int kt = 0; kt < 7; ++kt)
#pragma unroll
    for (int nt = 0; nt < 6; ++nt)
      asm volatile("" : "+v"(wfr[kt][nt]));

  // n-gate b_hh only (r/z b_hh folded into gateXp by gate_gemm)
  float bh2[2];
#pragma unroll
  for (int jt = 0; jt < 2; ++jt)
    bh2[jt] = bf2f(Bhh[dir * G3 + 512 + wv * 32 + jt * 16 + l15]);

  // ---- h_prev in registers; seed hbuf[1] (read by t=0 MFMA) ----
  float hprev[2][4];
#pragma unroll
  for (int jt = 0; jt < 2; ++jt)
#pragma unroll
    for (int r = 0; r < 4; ++r) {
      int j = wv * 32 + jt * 16 + l15;
      int m = quad * 4 + r;
      u16 hv = H0[((size_t)(layer * 2 + dir) * NB + bg * 16 + m) * HID + j];
      hprev[jt][r] = bf2f(hv);
      int ch = j >> 3;
      int sw = (ch & 24) | ((ch & 7) ^ (m & 7));
      *(u16*)((char*)hbuf[1] + m * 512 + sw * 16 + (j & 7) * 2) = hv;
    }
  __syncthreads();

  // layerOut staging identity for this thread (one 16B chunk of h per step)
  const int ms = tid >> 5;             // batch row 0..15
  const int cs = tid & 31;             // stored (swizzled) chunk index
  const int cj = (cs & 24) | ((cs & 7) ^ (ms & 7));   // logical j-chunk
  u16* loutBase =
      layerOut + ((size_t)(bg * 16 + ms)) * 512 + dir * 256 + cj * 8;

  for (int t = 0; t < S_LEN; ++t) {
    const int s = dir ? (S_LEN - 1 - t) : t;

    // ---- staged layerOut store for h(t-1): 1 ds_read_b128 + 1 16B store ----
    if (t > 0) {
      const int sp = dir ? (S_LEN - t) : (t - 1);
      bf16x8 hv = *(const bf16x8*)((const char*)hbuf[(t & 1) ^ 1] +
                                   ms * 512 + cs * 16);
      *(bf16x8*)(loutBase + (size_t)sp * NB * 512) = hv;
    }

    // ---- x-gate vector loads (permuted layout; overlap MFMA phase) ----
    const u16* xp =
        gateXp + (((((size_t)dir * 512 + s) * 4 + bg) * 3 * 8 + wv) * 64 + lane) * 8;
    bf16x8 xr = *(const bf16x8*)(xp);
    bf16x8 xz = *(const bf16x8*)(xp + 4096);
    bf16x8 xn = *(const bf16x8*)(xp + 8192);

    // ---- MFMA phase: preacts for this wave's 6 n-tiles ----
    const char* hrd = (const char*)hbuf[(t & 1) ^ 1];
    floatx4 acc[6];
#pragma unroll
    for (int nt = 0; nt < 6; ++nt) {
      if (nt < 4) {
        floatx4 z = {0.0f, 0.0f, 0.0f, 0.0f};
        acc[nt] = z;
      } else {
        floatx4 v = {bh2[nt - 4], bh2[nt - 4], bh2[nt - 4], bh2[nt - 4]};
        acc[nt] = v;
      }
    }
#pragma unroll
    for (int kt = 0; kt < 8; ++kt) {
      bf16x8 af = *(const bf16x8*)(hrd + l15 * 512 + (kt >> 1) * 128 +
                                   (((kt & 1) * 4 + quad) ^ (l15 & 7)) * 16);
      if (kt < 7) {
#pragma unroll
        for (int nt = 0; nt < 6; ++nt)
          acc[nt] = __builtin_amdgcn_mfma_f32_16x16x32_bf16(af, wfr[kt][nt],
                                                            acc[nt], 0, 0, 0);
      } else {
#pragma unroll
        for (int nt = 0; nt < 6; ++nt) {
          int n = (nt >> 1) * 256 + wv * 32 + (nt & 1) * 16 + l15;
          bf16x8 bw = *(const bf16x8*)((const char*)whT + n * 64 +
                                       ((quad ^ (l15 & 3)) * 16));
          acc[nt] = __builtin_amdgcn_mfma_f32_16x16x32_bf16(af, bw,
                                                            acc[nt], 0, 0, 0);
        }
      }
    }

    // ---- gate phase: fully in-register (lane owns (m=quad*4+r, j)) ----
    char* hwr = (char*)hbuf[t & 1];
#pragma unroll
    for (int jt = 0; jt < 2; ++jt)
#pragma unroll
      for (int r = 0; r < 4; ++r) {
        int e = jt * 4 + r;
        float xrf = bf2f((u16)xr[e]);
        float xzf = bf2f((u16)xz[e]);
        float xnf = bf2f((u16)xn[e]);
        float rg = fsigmoid(xrf + acc[0 + jt][r]);
        float zg = fsigmoid(xzf + acc[2 + jt][r]);
        float ng = ftanh(xnf + rg * acc[4 + jt][r]);
        float h  = (1.0f - zg) * ng + zg * hprev[jt][r];
        hprev[jt][r] = h;
        int j  = wv * 32 + jt * 16 + l15;
        int m  = quad * 4 + r;
        int ch = j >> 3;
        int sw = (ch & 24) | ((ch & 7) ^ (m & 7));
        *(u16*)(hwr + m * 512 + sw * 16 + (j & 7) * 2) = f2bf(h);
      }

    // LDS-drain-only barrier: global loads/stores stay in flight across it.
    asm volatile("s_waitcnt lgkmcnt(0)\n\ts_barrier" ::: "memory");
  }

  // ---- epilogue: store h(S_LEN-1) to layerOut + hNs ----
  {
    const int sp = dir ? 0 : (S_LEN - 1);
    bf16x8 hv = *(const bf16x8*)((const char*)hbuf[(S_LEN & 1) ^ 1] +
                                 ms * 512 + cs * 16);
    *(bf16x8*)(loutBase + (size_t)sp * NB * 512) = hv;
#pragma unroll
    for (int jt = 0; jt < 2; ++jt)
#pragma unroll
      for (int r = 0; r < 4; ++r) {
        int j = wv * 32 + jt * 16 + l15;
        int m = quad * 4 + r;
        hNs[((size_t)(layer * 2 + dir) * NB + bg * 16 + m) * HID + j] =
            hprev[jt][r];
      }
  }
}

// ---------------------------------------------------------------------------
extern "C" void kernel_launch(void* const* d_in, const int* in_sizes, int n_in,
                              void* d_out, int out_size, void* d_ws, size_t ws_size,
                              hipStream_t stream) {
  (void)n_in; (void)ws_size;
  char* ws = (char*)d_ws;
  int*   flag  = (int*)ws;
  float* hNs   = (float*)(ws + 4096);
  u16*   h0C   = (u16*)(ws + (1u << 20));
  u16*   wih0C = h0C   + 196608;
  u16*   wihC  = wih0C + 196608;
  u16*   whhC  = wihC  + 3932160;
  u16*   bihC  = whhC  + 2359296;
  u16*   bhhC  = bihC  + 9216;
  u16*   gateXp = (u16*)(ws + (16u  << 20));
  u16*   bufA   = (u16*)(ws + (112u << 20));
  u16*   bufB   = (u16*)(ws + (144u << 20));
  u16*   xC     = bufB;  // aliased; layer-0 gemm consumes it before bufB written

  detect_fp32<<<1, 1024, 0, stream>>>((const u16*)d_in[0], 262144, flag);
  cvt<<<512, 256, 0, stream>>>(d_in[0], xC,    in_sizes[0], flag);
  cvt<<<256, 256, 0, stream>>>(d_in[1], h0C,   in_sizes[1], flag);
  cvt<<<256, 256, 0, stream>>>(d_in[2], wih0C, in_sizes[2], flag);
  cvt<<<512, 256, 0, stream>>>(d_in[3], wihC,  in_sizes[3], flag);
  cvt<<<512, 256, 0, stream>>>(d_in[4], whhC,  in_sizes[4], flag);
  cvt<<< 64, 256, 0, stream>>>(d_in[5], bihC,  in_sizes[5], flag);
  cvt<<< 64, 256, 0, stream>>>(d_in[6], bhhC,  in_sizes[6], flag);

  for (int layer = 0; layer < NLAYER; ++layer) {
    const u16* inp = (layer == 0) ? xC : ((layer & 1) ? bufA : bufB);
    u16* outBuf    = (layer & 1) ? bufB : bufA;

    const int K = (layer == 0) ? 128 : 512;
    const u16* W = (layer == 0) ? wih0C
                                : (wihC + (size_t)(layer - 1) * 2 * G3 * 512);
    dim3 grid(256, 6, 2);
    gate_gemm<<<grid, 256, 0, stream>>>(inp, W, bihC + (size_t)layer * 2 * G3,
                                        bhhC + (size_t)layer * 2 * G3, gateXp, K);
    gru_scan<<<8, 512, 0, stream>>>(gateXp, whhC + (size_t)layer * 2 * G3 * HID,
                                    bhhC + (size_t)layer * 2 * G3, h0C,
                                    outBuf, hNs, layer);
  }
  write_out<<<(out_size + 255) / 256, 256, 0, stream>>>(hNs, d_out, out_size, flag);
}